// Round 18
// baseline (493.076 us; speedup 1.0000x reference)
//
#include <hip/hip_runtime.h>

#define NN 50000
#define NE 800000
#define NG 64
#define NB ((NN + 255) / 256)   // 196 scan blocks
#define WROW 193   // i-major weight row stride (dwords); odd -> conflict-free
#define NDB 512    // degree buckets for node counting-sort

// ---------------------------------------------------------------------------
// deg histogram (int)
// ---------------------------------------------------------------------------
__global__ __launch_bounds__(256) void histk(const int* __restrict__ dst,
                                             int* __restrict__ deg) {
    int e = blockIdx.x * 256 + threadIdx.x;
    if (e < NE) atomicAdd(&deg[dst[e]], 1);
}

// ---------------------------------------------------------------------------
// decoupled scan, stage 1: per-block (256-elem) sums of deg
// ---------------------------------------------------------------------------
__global__ __launch_bounds__(256) void bsumk(const int* __restrict__ deg,
                                             int* __restrict__ bsum) {
    int idx = blockIdx.x * 256 + threadIdx.x;
    int v = (idx < NN) ? deg[idx] : 0;
#pragma unroll
    for (int off = 32; off > 0; off >>= 1) v += __shfl_down(v, off);
    __shared__ int ws[4];
    int lane = threadIdx.x & 63, w = threadIdx.x >> 6;
    if (lane == 0) ws[w] = v;
    __syncthreads();
    if (threadIdx.x == 0) bsum[blockIdx.x] = ws[0] + ws[1] + ws[2] + ws[3];
}

// ---------------------------------------------------------------------------
// stage 2: exclusive scan of the NB block sums (single tiny block)
// ---------------------------------------------------------------------------
__global__ __launch_bounds__(256) void bscank(const int* __restrict__ bsum,
                                              int* __restrict__ boffs) {
    int tid = threadIdx.x;
    int v = (tid < NB) ? bsum[tid] : 0;
    int lane = tid & 63, w = tid >> 6;
    int t = v;
#pragma unroll
    for (int off = 1; off < 64; off <<= 1) {
        int u = __shfl_up(t, off);
        if (lane >= off) t += u;
    }
    __shared__ int ws[4];
    if (lane == 63) ws[w] = t;
    __syncthreads();
    int add = 0;
    for (int k = 0; k < w; k++) add += ws[k];
    if (tid < NB) boffs[tid] = add + t - v;   // exclusive prefix
}

// ---------------------------------------------------------------------------
// stage 3: in-block exclusive scan + block offset -> row[NN+1], cur[NN]
// ---------------------------------------------------------------------------
__global__ __launch_bounds__(256) void fscank(const int* __restrict__ deg,
                                              const int* __restrict__ boffs,
                                              int* __restrict__ row,
                                              int* __restrict__ cur) {
    int idx = blockIdx.x * 256 + threadIdx.x;
    int v = (idx < NN) ? deg[idx] : 0;
    int lane = threadIdx.x & 63, w = threadIdx.x >> 6;
    int t = v;
#pragma unroll
    for (int off = 1; off < 64; off <<= 1) {
        int u = __shfl_up(t, off);
        if (lane >= off) t += u;
    }
    __shared__ int ws[4];
    if (lane == 63) ws[w] = t;
    __syncthreads();
    int add = boffs[blockIdx.x];
    for (int k = 0; k < w; k++) add += ws[k];
    int ex = add + t - v;
    if (idx < NN) { row[idx] = ex; cur[idx] = ex; }
    else if (idx == NN) row[NN] = ex;   // == NE
}

// ---------------------------------------------------------------------------
// degree counting-sort: histogram -> scan -> scatter node ids
// Blocks of fusedk then see 16 near-equal-degree nodes -> no wave divergence
// (E[max of 4 Poisson(16)] ~ 20.7 vs mean 16 was ~23% wasted edge-loop slots).
// ---------------------------------------------------------------------------
__global__ __launch_bounds__(256) void dhistk(const int* __restrict__ deg,
                                              int* __restrict__ dh) {
    int v = blockIdx.x * 256 + threadIdx.x;
    if (v < NN) {
        int d = deg[v]; if (d > NDB - 1) d = NDB - 1;
        atomicAdd(&dh[d], 1);
    }
}

__global__ __launch_bounds__(512) void dscank(const int* __restrict__ dh,
                                              int* __restrict__ dcur) {
    int tid = threadIdx.x;
    int v = dh[tid];
    int lane = tid & 63, w = tid >> 6;
    int t = v;
#pragma unroll
    for (int off = 1; off < 64; off <<= 1) {
        int u = __shfl_up(t, off);
        if (lane >= off) t += u;
    }
    __shared__ int ws[8];
    if (lane == 63) ws[w] = t;
    __syncthreads();
    int add = 0;
    for (int k = 0; k < w; k++) add += ws[k];
    dcur[tid] = add + t - v;   // exclusive prefix
}

__global__ __launch_bounds__(256) void dscatk(const int* __restrict__ deg,
                                              int* __restrict__ dcur,
                                              int* __restrict__ order) {
    int v = blockIdx.x * 256 + threadIdx.x;
    if (v < NN) {
        int d = deg[v]; if (d > NDB - 1) d = NDB - 1;
        int pos = atomicAdd(&dcur[d], 1);
        order[pos] = v;
    }
}

// ---------------------------------------------------------------------------
// scatter edges into CSR order as 64B-aligned full-line records (R10 exact):
// rec[pos*16 + 0..15] = { as_float(src), ea0..ea7, 0,...,0 }
// ---------------------------------------------------------------------------
__global__ __launch_bounds__(256) void scatk(const int* __restrict__ src,
                                             const int* __restrict__ dst,
                                             const float* __restrict__ ea,
                                             int* __restrict__ cur,
                                             float* __restrict__ rec) {
    int e = blockIdx.x * 256 + threadIdx.x;
    if (e >= NE) return;
    int d = dst[e];
    int pos = atomicAdd(&cur[d], 1);
    float4 a = *(const float4*)(ea + (size_t)e * 8);
    float4 b = *(const float4*)(ea + (size_t)e * 8 + 4);
    float4* r = (float4*)(rec + (size_t)pos * 16);
    float4 r0; r0.x = __int_as_float(src[e]); r0.y = a.x; r0.z = a.y; r0.w = a.z;
    float4 r1; r1.x = a.w; r1.y = b.x; r1.z = b.y; r1.w = b.z;
    float4 r2; r2.x = b.w; r2.y = 0.f; r2.z = 0.f; r2.w = 0.f;
    float4 r3; r3.x = 0.f; r3.y = 0.f; r3.z = 0.f; r3.w = 0.f;
    r[0] = r0; r[1] = r1; r[2] = r2; r[3] = r3;
}

// ---------------------------------------------------------------------------
// fused edge+node layer (R17 structure; nodes taken from degree-sorted order).
// Edge loop = R10 exact; node phase = in-register partials + shfl butterfly.
// Writes out[v_orig] (scattered 64B per group; L2-absorbed).
// ---------------------------------------------------------------------------
__global__ __launch_bounds__(256) void fusedk(const float* __restrict__ xin,
                                              const int* __restrict__ row,
                                              const float* __restrict__ rec,
                                              const int* __restrict__ order,
                                              const float* __restrict__ we,
                                              const float* __restrict__ be,
                                              const float* __restrict__ root,
                                              const float* __restrict__ bias,
                                              float* __restrict__ out) {
    __shared__ float wlds[16 * WROW];
    __shared__ float bs[16];
    int tid = threadIdx.x;
    for (int idx = tid; idx < 2048; idx += 256) {
        int f = idx >> 8, rest = idx & 255, i = rest >> 4, o = rest & 15;
        wlds[i * WROW + o * 12 + f] = we[idx];
    }
    {
        int i = tid >> 4, o = tid & 15;
        wlds[i * WROW + o * 12 + 8] = be[tid];
        wlds[i * WROW + o * 12 + 9] = root[tid];
    }
    if (tid < 16) bs[tid] = bias[tid];
    __syncthreads();

    int g = tid >> 4, t = tid & 15;
    int v = order[blockIdx.x * 16 + g];
    int r0 = row[v], r1 = row[v + 1];

    float p0 = 0.f, p1 = 0.f, p2 = 0.f, p3 = 0.f;
    float p4 = 0.f, p5 = 0.f, p6 = 0.f, p7 = 0.f, s = 0.f;

    // ---- edge loop: R10 exact ----
    int pos = r0;
    int pend = r0 + ((r1 - r0) & ~3);
    for (; pos < pend; pos += 4) {
        const float* q0 = rec + (size_t)(pos + 0) * 16;
        const float* q1 = rec + (size_t)(pos + 1) * 16;
        const float* q2 = rec + (size_t)(pos + 2) * 16;
        const float* q3 = rec + (size_t)(pos + 3) * 16;
        float4 a0 = *(const float4*)q0; float4 b0 = *(const float4*)(q0 + 4); float e0 = q0[8];
        float4 a1 = *(const float4*)q1; float4 b1 = *(const float4*)(q1 + 4); float e1 = q1[8];
        float4 a2 = *(const float4*)q2; float4 b2 = *(const float4*)(q2 + 4); float e2 = q2[8];
        float4 a3 = *(const float4*)q3; float4 b3 = *(const float4*)(q3 + 4); float e3 = q3[8];
        float x0 = xin[(size_t)__float_as_int(a0.x) * 16 + t];
        float x1 = xin[(size_t)__float_as_int(a1.x) * 16 + t];
        float x2 = xin[(size_t)__float_as_int(a2.x) * 16 + t];
        float x3 = xin[(size_t)__float_as_int(a3.x) * 16 + t];
        p0 += a0.y * x0; p1 += a0.z * x0; p2 += a0.w * x0; p3 += b0.x * x0;
        p4 += b0.y * x0; p5 += b0.z * x0; p6 += b0.w * x0; p7 += e0 * x0; s += x0;
        p0 += a1.y * x1; p1 += a1.z * x1; p2 += a1.w * x1; p3 += b1.x * x1;
        p4 += b1.y * x1; p5 += b1.z * x1; p6 += b1.w * x1; p7 += e1 * x1; s += x1;
        p0 += a2.y * x2; p1 += a2.z * x2; p2 += a2.w * x2; p3 += b2.x * x2;
        p4 += b2.y * x2; p5 += b2.z * x2; p6 += b2.w * x2; p7 += e2 * x2; s += x2;
        p0 += a3.y * x3; p1 += a3.z * x3; p2 += a3.w * x3; p3 += b3.x * x3;
        p4 += b3.y * x3; p5 += b3.z * x3; p6 += b3.w * x3; p7 += e3 * x3; s += x3;
    }
    for (; pos < r1; ++pos) {
        const float* q = rec + (size_t)pos * 16;
        float4 a = *(const float4*)q; float4 b = *(const float4*)(q + 4); float e8 = q[8];
        float xv = xin[(size_t)__float_as_int(a.x) * 16 + t];
        p0 += a.y * xv; p1 += a.z * xv; p2 += a.w * xv; p3 += b.x * xv;
        p4 += b.y * xv; p5 += b.z * xv; p6 += b.w * xv; p7 += e8 * xv; s += xv;
    }

    // ---- node phase: in-register partials + butterfly reduce ----
    int dg = r1 - r0;
    float inv = 1.0f / (float)(dg > 1 ? dg : 1);
    float xv = xin[(size_t)v * 16 + t];

    float a[16];
    const float* wr = wlds + t * WROW;
#pragma unroll
    for (int o = 0; o < 16; o++) {
        const float* w = wr + o * 12;
        float agg = w[0] * p0 + w[1] * p1 + w[2] * p2 + w[3] * p3 +
                    w[4] * p4 + w[5] * p5 + w[6] * p6 + w[7] * p7 + w[8] * s;
        a[o] = agg * inv + w[9] * xv;
    }

    {
        int bit = (t >> 3) & 1;
#pragma unroll
        for (int k = 0; k < 8; k++) {
            float snd = bit ? a[k] : a[k + 8];
            float kp  = bit ? a[k + 8] : a[k];
            a[k] = kp + __shfl_xor(snd, 8);
        }
        bit = (t >> 2) & 1;
#pragma unroll
        for (int k = 0; k < 4; k++) {
            float snd = bit ? a[k] : a[k + 4];
            float kp  = bit ? a[k + 4] : a[k];
            a[k] = kp + __shfl_xor(snd, 4);
        }
        bit = (t >> 1) & 1;
#pragma unroll
        for (int k = 0; k < 2; k++) {
            float snd = bit ? a[k] : a[k + 2];
            float kp  = bit ? a[k + 2] : a[k];
            a[k] = kp + __shfl_xor(snd, 2);
        }
        bit = t & 1;
        {
            float snd = bit ? a[0] : a[1];
            float kp  = bit ? a[1] : a[0];
            a[0] = kp + __shfl_xor(snd, 1);
        }
    }
    out[(size_t)v * 16 + t] = a[0] + bs[t];
}

// ---------------------------------------------------------------------------
// pool kernel: original node order (batch-sorted), block of 16 nodes, LDS
// accumulate per graph slot then one atomic per slot.
// ---------------------------------------------------------------------------
__global__ __launch_bounds__(256) void poolk(const float* __restrict__ h2,
                                             const int* __restrict__ batch,
                                             float* __restrict__ gsum,
                                             float* __restrict__ gcnt) {
    __shared__ float gacc[16][16];
    __shared__ int gcnta[16];
    int tid = threadIdx.x;
    gacc[tid >> 4][tid & 15] = 0.f;
    if (tid < 16) gcnta[tid] = 0;
    __syncthreads();
    int g = tid >> 4, t = tid & 15;
    int v = blockIdx.x * 16 + g;
    float h = h2[(size_t)v * 16 + t];
    int bmin = batch[blockIdx.x * 16];
    int b = batch[v];
    int slot = b - bmin;
    if (slot < 16) {
        atomicAdd(&gacc[slot][t], h);
        if (t == 0) atomicAdd(&gcnta[slot], 1);
    } else {
        atomicAdd(&gsum[(size_t)b * 16 + t], h);
        if (t == 0) atomicAdd(&gcnt[b], 1.0f);
    }
    __syncthreads();
    if (gcnta[g] > 0) {
        atomicAdd(&gsum[(size_t)(bmin + g) * 16 + t], gacc[g][t]);
        if (t == 0) atomicAdd(&gcnt[bmin + g], (float)gcnta[g]);
    }
}

// ---------------------------------------------------------------------------
// final divide over all NG*16 = 1024 outputs
// ---------------------------------------------------------------------------
__global__ void fink(const float* __restrict__ gsum,
                     const float* __restrict__ gcnt,
                     float* __restrict__ out) {
    int i = blockIdx.x * 256 + threadIdx.x;
    if (i < NG * 16) out[i] = gsum[i] / fmaxf(gcnt[i >> 4], 1.0f);
}

extern "C" void kernel_launch(void* const* d_in, const int* in_sizes, int n_in,
                              void* d_out, int out_size, void* d_ws, size_t ws_size,
                              hipStream_t stream) {
    const float* x     = (const float*)d_in[0];
    const int*   ei    = (const int*)d_in[1];
    const float* ea    = (const float*)d_in[2];
    const int*   batch = (const int*)d_in[3];
    const float* we1   = (const float*)d_in[4];
    const float* be1   = (const float*)d_in[5];
    const float* root1 = (const float*)d_in[6];
    const float* bias1 = (const float*)d_in[7];
    const float* we2   = (const float*)d_in[8];
    const float* be2   = (const float*)d_in[9];
    const float* root2 = (const float*)d_in[10];
    const float* bias2 = (const float*)d_in[11];

    float* ws = (float*)d_ws;
    float* rec  = ws;                                   // NE*16 floats, 64B-aligned
    float* h1   = rec + (size_t)NE * 16;                // NN*16
    float* h2   = h1 + (size_t)NN * 16;                 // NN*16
    int*   order= (int*)(h2 + (size_t)NN * 16);         // NN
    int*   row  = order + NN;                           // NN+1
    int*   cur  = row + NN + 1;                         // NN
    int*   deg  = cur + NN;                             // NN  <- memset from here
    int*   bsum = deg + NN;                             // NB
    int*   boffs= bsum + NB;                            // NB
    int*   dh   = boffs + NB;                           // NDB
    int*   dcur = dh + NDB;                             // NDB (written by dscank)
    float* gsum = (float*)(dcur + NDB);                 // NG*16
    float* gcnt = gsum + NG * 16;                       // NG

    // zero deg + bsum + boffs + dh + dcur + gsum + gcnt (contiguous)
    hipMemsetAsync(deg, 0,
                   (size_t)(NN + 2 * NB + 2 * NDB + NG * 16 + NG) * 4, stream);

    const int* src = ei;
    const int* dst = ei + NE;

    int gE = (NE + 255) / 256;   // 3125
    int gV = NN / 16;            // 3125 (exact)

    histk<<<gE, 256, 0, stream>>>(dst, deg);
    bsumk<<<NB, 256, 0, stream>>>(deg, bsum);
    bscank<<<1, 256, 0, stream>>>(bsum, boffs);
    fscank<<<NB, 256, 0, stream>>>(deg, boffs, row, cur);
    // degree counting-sort (overlaps scatk's latency on the same stream order)
    dhistk<<<NB, 256, 0, stream>>>(deg, dh);
    dscank<<<1, 512, 0, stream>>>(dh, dcur);
    dscatk<<<NB, 256, 0, stream>>>(deg, dcur, order);
    scatk<<<gE, 256, 0, stream>>>(src, dst, ea, cur, rec);

    // layer 1
    fusedk<<<gV, 256, 0, stream>>>(x, row, rec, order, we1, be1, root1, bias1, h1);
    // layer 2
    fusedk<<<gV, 256, 0, stream>>>(h1, row, rec, order, we2, be2, root2, bias2, h2);
    // pooling (original node order)
    poolk<<<gV, 256, 0, stream>>>(h2, batch, gsum, gcnt);

    fink<<<4, 256, 0, stream>>>(gsum, gcnt, (float*)d_out);
}

// Round 19
// 184.757 us; speedup vs baseline: 2.6688x; 2.6688x over previous
//
#include <hip/hip_runtime.h>

#define NN 50000
#define NE 800000
#define NG 64
#define NB ((NN + 255) / 256)   // 196 scan blocks
#define WSTR 164   // per-o weight column stride (floats): 160 used + pad, 16B-aligned

// ---------------------------------------------------------------------------
// deg histogram (int)
// ---------------------------------------------------------------------------
__global__ __launch_bounds__(256) void histk(const int* __restrict__ dst,
                                             int* __restrict__ deg) {
    int e = blockIdx.x * 256 + threadIdx.x;
    if (e < NE) atomicAdd(&deg[dst[e]], 1);
}

// ---------------------------------------------------------------------------
// decoupled scan, stage 1: per-block (256-elem) sums of deg
// ---------------------------------------------------------------------------
__global__ __launch_bounds__(256) void bsumk(const int* __restrict__ deg,
                                             int* __restrict__ bsum) {
    int idx = blockIdx.x * 256 + threadIdx.x;
    int v = (idx < NN) ? deg[idx] : 0;
#pragma unroll
    for (int off = 32; off > 0; off >>= 1) v += __shfl_down(v, off);
    __shared__ int ws[4];
    int lane = threadIdx.x & 63, w = threadIdx.x >> 6;
    if (lane == 0) ws[w] = v;
    __syncthreads();
    if (threadIdx.x == 0) bsum[blockIdx.x] = ws[0] + ws[1] + ws[2] + ws[3];
}

// ---------------------------------------------------------------------------
// stage 2: exclusive scan of the NB block sums (single tiny block)
// ---------------------------------------------------------------------------
__global__ __launch_bounds__(256) void bscank(const int* __restrict__ bsum,
                                              int* __restrict__ boffs) {
    int tid = threadIdx.x;
    int v = (tid < NB) ? bsum[tid] : 0;
    int lane = tid & 63, w = tid >> 6;
    int t = v;
#pragma unroll
    for (int off = 1; off < 64; off <<= 1) {
        int u = __shfl_up(t, off);
        if (lane >= off) t += u;
    }
    __shared__ int ws[4];
    if (lane == 63) ws[w] = t;
    __syncthreads();
    int add = 0;
    for (int k = 0; k < w; k++) add += ws[k];
    if (tid < NB) boffs[tid] = add + t - v;   // exclusive prefix
}

// ---------------------------------------------------------------------------
// stage 3: in-block exclusive scan + block offset -> row[NN+1], cur[NN]
// ---------------------------------------------------------------------------
__global__ __launch_bounds__(256) void fscank(const int* __restrict__ deg,
                                              const int* __restrict__ boffs,
                                              int* __restrict__ row,
                                              int* __restrict__ cur) {
    int idx = blockIdx.x * 256 + threadIdx.x;
    int v = (idx < NN) ? deg[idx] : 0;
    int lane = threadIdx.x & 63, w = threadIdx.x >> 6;
    int t = v;
#pragma unroll
    for (int off = 1; off < 64; off <<= 1) {
        int u = __shfl_up(t, off);
        if (lane >= off) t += u;
    }
    __shared__ int ws[4];
    if (lane == 63) ws[w] = t;
    __syncthreads();
    int add = boffs[blockIdx.x];
    for (int k = 0; k < w; k++) add += ws[k];
    int ex = add + t - v;
    if (idx < NN) { row[idx] = ex; cur[idx] = ex; }
    else if (idx == NN) row[NN] = ex;   // == NE
}

// ---------------------------------------------------------------------------
// scatter edges into CSR order as 64B-aligned full-line records:
// rec[pos*16 + 0..15] = { as_float(src), ea0..ea7, 0,...,0 }
// ---------------------------------------------------------------------------
__global__ __launch_bounds__(256) void scatk(const int* __restrict__ src,
                                             const int* __restrict__ dst,
                                             const float* __restrict__ ea,
                                             int* __restrict__ cur,
                                             float* __restrict__ rec) {
    int e = blockIdx.x * 256 + threadIdx.x;
    if (e >= NE) return;
    int d = dst[e];
    int pos = atomicAdd(&cur[d], 1);
    float4 a = *(const float4*)(ea + (size_t)e * 8);
    float4 b = *(const float4*)(ea + (size_t)e * 8 + 4);
    float4* r = (float4*)(rec + (size_t)pos * 16);
    float4 r0; r0.x = __int_as_float(src[e]); r0.y = a.x; r0.z = a.y; r0.w = a.z;
    float4 r1; r1.x = a.w; r1.y = b.x; r1.z = b.y; r1.w = b.z;
    float4 r2; r2.x = b.w; r2.y = 0.f; r2.z = 0.f; r2.w = 0.f;
    float4 r3; r3.x = 0.f; r3.y = 0.f; r3.z = 0.f; r3.w = 0.f;
    r[0] = r0; r[1] = r1; r[2] = r2; r[3] = r3;
}

// ---------------------------------------------------------------------------
// fused edge+node layer. Edge loop unrolled x4: 4 independent rec streams +
// 4 independent x-gathers in flight per 16-thread group (best measured).
// ---------------------------------------------------------------------------
template <bool POOL>
__global__ __launch_bounds__(256) void fusedk(const float* __restrict__ xin,
                                              const int* __restrict__ row,
                                              const float* __restrict__ rec,
                                              const float* __restrict__ we,
                                              const float* __restrict__ be,
                                              const float* __restrict__ root,
                                              const float* __restrict__ bias,
                                              const int* __restrict__ batch,
                                              float* __restrict__ out,
                                              float* __restrict__ gsum,
                                              float* __restrict__ gcnt) {
    __shared__ float wt[16 * WSTR];
    __shared__ float pls[16][WSTR];
    __shared__ float bs[16];
    __shared__ float gacc[16][16];
    __shared__ int gcnta[16];
    int tid = threadIdx.x;
    for (int idx = tid; idx < 2048; idx += 256) {
        int f = idx >> 8; int i = (idx >> 4) & 15; int o = idx & 15;
        wt[o * WSTR + f * 16 + i] = we[idx];
    }
    {
        int i = tid >> 4, o = tid & 15;
        wt[o * WSTR + 128 + i] = be[tid];
        wt[o * WSTR + 144 + i] = root[tid];
    }
    if (tid < 16) bs[tid] = bias[tid];
    if (POOL) {
        gacc[tid >> 4][tid & 15] = 0.f;
        if (tid < 16) gcnta[tid] = 0;
    }

    int g = tid >> 4, t = tid & 15;
    int v = blockIdx.x * 16 + g;
    int r0 = row[v], r1 = row[v + 1];

    float p0 = 0.f, p1 = 0.f, p2 = 0.f, p3 = 0.f;
    float p4 = 0.f, p5 = 0.f, p6 = 0.f, p7 = 0.f, s = 0.f;

    int pos = r0;
    int pend = r0 + ((r1 - r0) & ~3);
    for (; pos < pend; pos += 4) {
        const float* q0 = rec + (size_t)(pos + 0) * 16;
        const float* q1 = rec + (size_t)(pos + 1) * 16;
        const float* q2 = rec + (size_t)(pos + 2) * 16;
        const float* q3 = rec + (size_t)(pos + 3) * 16;
        float4 a0 = *(const float4*)q0; float4 b0 = *(const float4*)(q0 + 4); float e0 = q0[8];
        float4 a1 = *(const float4*)q1; float4 b1 = *(const float4*)(q1 + 4); float e1 = q1[8];
        float4 a2 = *(const float4*)q2; float4 b2 = *(const float4*)(q2 + 4); float e2 = q2[8];
        float4 a3 = *(const float4*)q3; float4 b3 = *(const float4*)(q3 + 4); float e3 = q3[8];
        float x0 = xin[(size_t)__float_as_int(a0.x) * 16 + t];
        float x1 = xin[(size_t)__float_as_int(a1.x) * 16 + t];
        float x2 = xin[(size_t)__float_as_int(a2.x) * 16 + t];
        float x3 = xin[(size_t)__float_as_int(a3.x) * 16 + t];
        p0 += a0.y * x0; p1 += a0.z * x0; p2 += a0.w * x0; p3 += b0.x * x0;
        p4 += b0.y * x0; p5 += b0.z * x0; p6 += b0.w * x0; p7 += e0 * x0; s += x0;
        p0 += a1.y * x1; p1 += a1.z * x1; p2 += a1.w * x1; p3 += b1.x * x1;
        p4 += b1.y * x1; p5 += b1.z * x1; p6 += b1.w * x1; p7 += e1 * x1; s += x1;
        p0 += a2.y * x2; p1 += a2.z * x2; p2 += a2.w * x2; p3 += b2.x * x2;
        p4 += b2.y * x2; p5 += b2.z * x2; p6 += b2.w * x2; p7 += e2 * x2; s += x2;
        p0 += a3.y * x3; p1 += a3.z * x3; p2 += a3.w * x3; p3 += b3.x * x3;
        p4 += b3.y * x3; p5 += b3.z * x3; p6 += b3.w * x3; p7 += e3 * x3; s += x3;
    }
    for (; pos < r1; ++pos) {
        const float* q = rec + (size_t)pos * 16;
        float4 a = *(const float4*)q; float4 b = *(const float4*)(q + 4); float e8 = q[8];
        float xv = xin[(size_t)__float_as_int(a.x) * 16 + t];
        p0 += a.y * xv; p1 += a.z * xv; p2 += a.w * xv; p3 += b.x * xv;
        p4 += b.y * xv; p5 += b.z * xv; p6 += b.w * xv; p7 += e8 * xv; s += xv;
    }

    pls[g][0 * 16 + t] = p0; pls[g][1 * 16 + t] = p1;
    pls[g][2 * 16 + t] = p2; pls[g][3 * 16 + t] = p3;
    pls[g][4 * 16 + t] = p4; pls[g][5 * 16 + t] = p5;
    pls[g][6 * 16 + t] = p6; pls[g][7 * 16 + t] = p7;
    pls[g][128 + t] = s;
    pls[g][144 + t] = xin[(size_t)v * 16 + t];
    __syncthreads();

    int o = t;
    const float4* pv = (const float4*)pls[g];
    const float4* wc = (const float4*)(wt + o * WSTR);
    float agg = 0.f;
#pragma unroll
    for (int k = 0; k < 36; k++) {        // 144 floats: we (128) + be*S (16)
        float4 a = pv[k]; float4 wv = wc[k];
        agg += a.x * wv.x + a.y * wv.y + a.z * wv.z + a.w * wv.w;
    }
    float r = 0.f;
#pragma unroll
    for (int k = 36; k < 40; k++) {       // root part (16 floats)
        float4 a = pv[k]; float4 wv = wc[k];
        r += a.x * wv.x + a.y * wv.y + a.z * wv.z + a.w * wv.w;
    }
    int dg = r1 - r0;
    float h = r + agg / (float)(dg > 1 ? dg : 1) + bs[o];

    if (!POOL) {
        out[(size_t)v * 16 + o] = h;
    } else {
        int bmin = batch[blockIdx.x * 16];
        int b = batch[v];
        int slot = b - bmin;
        if (slot < 16) {
            atomicAdd(&gacc[slot][o], h);
            if (o == 0) atomicAdd(&gcnta[slot], 1);
        } else {
            atomicAdd(&gsum[(size_t)b * 16 + o], h);
            if (o == 0) atomicAdd(&gcnt[b], 1.0f);
        }
        __syncthreads();
        if (gcnta[g] > 0) {
            atomicAdd(&gsum[(size_t)(bmin + g) * 16 + o], gacc[g][o]);
            if (o == 0) atomicAdd(&gcnt[bmin + g], (float)gcnta[g]);
        }
    }
}

// ---------------------------------------------------------------------------
// final divide over all NG*16 = 1024 outputs
// ---------------------------------------------------------------------------
__global__ void fink(const float* __restrict__ gsum,
                     const float* __restrict__ gcnt,
                     float* __restrict__ out) {
    int i = blockIdx.x * 256 + threadIdx.x;
    if (i < NG * 16) out[i] = gsum[i] / fmaxf(gcnt[i >> 4], 1.0f);
}

extern "C" void kernel_launch(void* const* d_in, const int* in_sizes, int n_in,
                              void* d_out, int out_size, void* d_ws, size_t ws_size,
                              hipStream_t stream) {
    const float* x     = (const float*)d_in[0];
    const int*   ei    = (const int*)d_in[1];
    const float* ea    = (const float*)d_in[2];
    const int*   batch = (const int*)d_in[3];
    const float* we1   = (const float*)d_in[4];
    const float* be1   = (const float*)d_in[5];
    const float* root1 = (const float*)d_in[6];
    const float* bias1 = (const float*)d_in[7];
    const float* we2   = (const float*)d_in[8];
    const float* be2   = (const float*)d_in[9];
    const float* root2 = (const float*)d_in[10];
    const float* bias2 = (const float*)d_in[11];

    float* ws = (float*)d_ws;
    float* rec  = ws;                                   // NE*16 floats, 64B-aligned
    float* h1   = rec + (size_t)NE * 16;                // NN*16
    int*   row  = (int*)(h1 + (size_t)NN * 16);         // NN+1
    int*   cur  = row + NN + 1;                         // NN
    int*   deg  = cur + NN;                             // NN
    int*   bsum = deg + NN;                             // NB
    int*   boffs= bsum + NB;                            // NB
    float* gsum = (float*)(boffs + NB);                 // NG*16
    float* gcnt = gsum + NG * 16;                       // NG

    // zero deg + bsum + boffs + gsum + gcnt (contiguous)
    hipMemsetAsync(deg, 0, (size_t)(NN + 2 * NB + NG * 16 + NG) * 4, stream);

    const int* src = ei;
    const int* dst = ei + NE;

    int gE = (NE + 255) / 256;   // 3125
    int gV = NN / 16;            // 3125 (exact)

    histk<<<gE, 256, 0, stream>>>(dst, deg);
    bsumk<<<NB, 256, 0, stream>>>(deg, bsum);
    bscank<<<1, 256, 0, stream>>>(bsum, boffs);
    fscank<<<NB, 256, 0, stream>>>(deg, boffs, row, cur);
    scatk<<<gE, 256, 0, stream>>>(src, dst, ea, cur, rec);

    // layer 1
    fusedk<false><<<gV, 256, 0, stream>>>(x, row, rec, we1, be1, root1, bias1,
                                          batch, h1, gsum, gcnt);
    // layer 2 (+ pooling)
    fusedk<true><<<gV, 256, 0, stream>>>(h1, row, rec, we2, be2, root2, bias2,
                                         batch, h1 /*unused*/, gsum, gcnt);

    fink<<<4, 256, 0, stream>>>(gsum, gcnt, (float*)d_out);
}